// Round 13
// baseline (2293.989 us; speedup 1.0000x reference)
//
#include <hip/hip_runtime.h>
#include <hip/hip_fp16.h>

#define TT 2048
#define BB 64
#define HH 128
#define GG 512   // 4H
#define CH 64    // chunk (timesteps per handshake)
#define NCH (TT / CH)
#define NPB 32   // producer (and consumer) block count; 2 batches per block

typedef _Float16 f16x8 __attribute__((ext_vector_type(8)));
typedef _Float16 f16x4 __attribute__((ext_vector_type(4)));
typedef float f32x4 __attribute__((ext_vector_type(4)));

__device__ __forceinline__ float sigm(float x) {
    return __builtin_amdgcn_rcpf(1.0f + __expf(-x));
}
__device__ __forceinline__ float tanh_f(float x) {
    return 1.0f - 2.0f * __builtin_amdgcn_rcpf(1.0f + __expf(2.0f * x));
}
// LDS-only barrier: no vmcnt drain (HIP __syncthreads drains all global ops).
__device__ __forceinline__ void bar_lds() {
    asm volatile("s_waitcnt lgkmcnt(0)\n\ts_barrier" ::: "memory");
}

__device__ __forceinline__ f16x8 load_frag(const float* rowp, int kt, int lh) {
    const float4* p4 = (const float4*)(rowp + kt * 32 + lh * 8);
    float4 a = p4[0], b = p4[1];
    f16x8 f;
    f[0] = (_Float16)a.x; f[1] = (_Float16)a.y; f[2] = (_Float16)a.z; f[3] = (_Float16)a.w;
    f[4] = (_Float16)b.x; f[5] = (_Float16)b.y; f[6] = (_Float16)b.z; f[7] = (_Float16)b.w;
    return f;
}

// Producer/consumer pipeline across blocks (r12 protocol, proven) + round-13
// DUAL-BATCH ILP: each block handles batches (b, b+32). The two recurrences
// are independent -> each wave interleaves two MFMA/activation chains per
// step, filling the dependency stalls that made r12's step ~1450 cyc. Weights
// (Bf/Bh/Bi, v,u0) are shared across the two batches; only av/acc/state
// double. One barrier and one flag per (block,chunk) covers both batches.
__global__ __launch_bounds__(512, 1) void k_pipe(
    const float* __restrict__ x, const int* __restrict__ lengths,
    const float* __restrict__ ff_w, const float* __restrict__ ff_b,
    const float* __restrict__ W_ih0, const float* __restrict__ W_hh0,
    const float* __restrict__ b0, const float* __restrict__ W_ih1,
    const float* __restrict__ W_hh1, const float* __restrict__ b1,
    _Float16* __restrict__ h0g, int* __restrict__ flags,
    float* __restrict__ pooled) {
    const int tid = threadIdx.x;
    const int w = tid >> 6;
    const int lane = tid & 63;
    const int c = lane & 15;
    const int lh = lane >> 4;
    const int un = 16 * w + c;
    const bool ard = (c == 0);     // A-frag reader lanes (M=1 row 0)
    const bool wr16 = (lane < 16); // C row m=0 lanes (lh==0)

    __shared__ float xs[2][TT];              // producer: 16 KB
    __shared__ _Float16 Hb0[2][2][HH];       // producer: [batch][buf][unit]
    __shared__ _Float16 Hb1[2][2][HH];       // consumer
    __shared__ _Float16 Qs[2][CH][GG];       // consumer: chunk gates, 128 KB

    if (blockIdx.x < NPB) {
        // ======================= PRODUCER: layer 0, batches (p, p+32) =====
        const int p = blockIdx.x;
        const int bA = p, bB = p + NPB;
        for (int i = tid; i < 2 * TT; i += 512)
            xs[i >> 11][i & (TT - 1)] = x[(i < TT ? bA : bB) * TT + (i & (TT - 1))];
        if (tid < 4 * HH) ((_Float16*)Hb0)[tid] = (_Float16)0.f;

        f16x8 Bf[4][4];
        float v[4], u0[4];
#pragma unroll
        for (int t2 = 0; t2 < 4; ++t2) {
            const int r = t2 * HH + un;
#pragma unroll
            for (int kt = 0; kt < 4; ++kt) Bf[t2][kt] = load_frag(W_hh0 + r * HH, kt, lh);
            const float4* wi4 = (const float4*)(W_ih0 + r * HH);
            const float4* fw4 = (const float4*)ff_w;
            const float4* fb4 = (const float4*)ff_b;
            float vv = 0.f, uu = 0.f;
#pragma unroll
            for (int m = 0; m < HH / 4; ++m) {
                float4 a = wi4[m], fw = fw4[m], fb = fb4[m];
                vv += a.x * fw.x + a.y * fw.y + a.z * fw.z + a.w * fw.w;
                uu += a.x * fb.x + a.y * fb.y + a.z * fb.z + a.w * fb.w;
            }
            v[t2] = vv;
            u0[t2] = uu + b0[r];
        }
#pragma unroll
        for (int t2 = 0; t2 < 4; ++t2)
#pragma unroll
            for (int kt = 0; kt < 4; ++kt) asm volatile("" : "+v"(Bf[t2][kt]));

        float cstA = 0.f, cstB = 0.f;
        f16x8 avA[4], avB[4];
#pragma unroll
        for (int kt = 0; kt < 4; ++kt) {
            avA[kt] = (f16x8){0, 0, 0, 0, 0, 0, 0, 0};
            avB[kt] = (f16x8){0, 0, 0, 0, 0, 0, 0, 0};
        }
        __syncthreads();

#define PSTEP(T_, RB_)                                                          \
    do {                                                                        \
        if (ard) {                                                              \
            _Pragma("unroll") for (int kt = 0; kt < 4; ++kt) {                  \
                avA[kt] = *(const f16x8*)&Hb0[0][RB_][kt * 32 + lh * 8];        \
                avB[kt] = *(const f16x8*)&Hb0[1][RB_][kt * 32 + lh * 8];        \
            }                                                                   \
        }                                                                       \
        const float xtA = xs[0][T_], xtB = xs[1][T_];                           \
        float pA[4], pB[4];                                                     \
        _Pragma("unroll") for (int t2 = 0; t2 < 4; ++t2) {                      \
            f32x4 aA, aB;                                                       \
            aA[0] = wr16 ? (xtA * v[t2] + u0[t2]) : 0.f;                        \
            aA[1] = 0.f; aA[2] = 0.f; aA[3] = 0.f;                              \
            aB[0] = wr16 ? (xtB * v[t2] + u0[t2]) : 0.f;                        \
            aB[1] = 0.f; aB[2] = 0.f; aB[3] = 0.f;                              \
            _Pragma("unroll") for (int kt = 0; kt < 4; ++kt) {                  \
                aA = __builtin_amdgcn_mfma_f32_16x16x32_f16(avA[kt],            \
                         Bf[t2][kt], aA, 0, 0, 0);                              \
                aB = __builtin_amdgcn_mfma_f32_16x16x32_f16(avB[kt],            \
                         Bf[t2][kt], aB, 0, 0, 0);                              \
            }                                                                   \
            pA[t2] = aA[0]; pB[t2] = aB[0];                                     \
        }                                                                       \
        {                                                                       \
            float gi = sigm(pA[0]), gf = sigm(pA[1]);                           \
            float gg = tanh_f(pA[2]), go = sigm(pA[3]);                         \
            cstA = gf * cstA + gi * gg;                                         \
            float hn = go * tanh_f(cstA);                                       \
            if (wr16) {                                                         \
                Hb0[0][(RB_) ^ 1][un] = (_Float16)hn;                           \
                __builtin_nontemporal_store(                                    \
                    (_Float16)hn, h0g + ((size_t)bA * TT + (T_)) * HH + un);    \
            }                                                                   \
        }                                                                       \
        {                                                                       \
            float gi = sigm(pB[0]), gf = sigm(pB[1]);                           \
            float gg = tanh_f(pB[2]), go = sigm(pB[3]);                         \
            cstB = gf * cstB + gi * gg;                                         \
            float hn = go * tanh_f(cstB);                                       \
            if (wr16) {                                                         \
                Hb0[1][(RB_) ^ 1][un] = (_Float16)hn;                           \
                __builtin_nontemporal_store(                                    \
                    (_Float16)hn, h0g + ((size_t)bB * TT + (T_)) * HH + un);    \
            }                                                                   \
        }                                                                       \
        bar_lds();                                                              \
    } while (0)

        for (int ch = 0; ch < NCH; ++ch) {
            const int t0 = ch * CH;
            for (int j = 0; j < CH; j += 2) {
                PSTEP(t0 + j, 0);
                PSTEP(t0 + j + 1, 1);
            }
            __syncthreads();  // drain both batches' NT stores before signaling
            if (tid == 0)
                __hip_atomic_store(&flags[p * NCH + ch], ch + 1, __ATOMIC_RELEASE,
                                   __HIP_MEMORY_SCOPE_AGENT);
        }
#undef PSTEP
    } else {
        // ======================= CONSUMER: layer 1, batches (p, p+32) =====
        const int p = blockIdx.x - NPB;
        const int bA = p, bB = p + NPB;
        if (tid < 4 * HH) ((_Float16*)Hb1)[tid] = (_Float16)0.f;

        f16x8 Bh[4][4];
        float bb1[4];
#pragma unroll
        for (int t2 = 0; t2 < 4; ++t2) {
#pragma unroll
            for (int kt = 0; kt < 4; ++kt)
                Bh[t2][kt] = load_frag(W_hh1 + (t2 * HH + un) * HH, kt, lh);
            bb1[t2] = b1[t2 * HH + un];
        }
#pragma unroll
        for (int t2 = 0; t2 < 4; ++t2)
#pragma unroll
            for (int kt = 0; kt < 4; ++kt) asm volatile("" : "+v"(Bh[t2][kt]));

        const int lenA = lengths[bA], lenB = lengths[bB];
        float cstA = 0.f, cstB = 0.f;
        float meanA = 0.f, meanB = 0.f, mxA = -1e30f, mxB = -1e30f;
        float lastA = 0.f, lastB = 0.f;
        f16x8 avA[4], avB[4];
#pragma unroll
        for (int kt = 0; kt < 4; ++kt) {
            avA[kt] = (f16x8){0, 0, 0, 0, 0, 0, 0, 0};
            avB[kt] = (f16x8){0, 0, 0, 0, 0, 0, 0, 0};
        }
        __syncthreads();

#define CSTEP(T_, RB_)                                                          \
    do {                                                                        \
        const int jj = (T_) & (CH - 1);                                         \
        f16x4 qA = *(const f16x4*)&Qs[0][jj][un * 4];                           \
        f16x4 qB = *(const f16x4*)&Qs[1][jj][un * 4];                           \
        if (ard) {                                                              \
            _Pragma("unroll") for (int kt = 0; kt < 4; ++kt) {                  \
                avA[kt] = *(const f16x8*)&Hb1[0][RB_][kt * 32 + lh * 8];        \
                avB[kt] = *(const f16x8*)&Hb1[1][RB_][kt * 32 + lh * 8];        \
            }                                                                   \
        }                                                                       \
        float pA[4], pB[4];                                                     \
        _Pragma("unroll") for (int t2 = 0; t2 < 4; ++t2) {                      \
            f32x4 aA, aB;                                                       \
            aA[0] = wr16 ? (float)qA[t2] : 0.f;                                 \
            aA[1] = 0.f; aA[2] = 0.f; aA[3] = 0.f;                              \
            aB[0] = wr16 ? (float)qB[t2] : 0.f;                                 \
            aB[1] = 0.f; aB[2] = 0.f; aB[3] = 0.f;                              \
            _Pragma("unroll") for (int kt = 0; kt < 4; ++kt) {                  \
                aA = __builtin_amdgcn_mfma_f32_16x16x32_f16(avA[kt],            \
                         Bh[t2][kt], aA, 0, 0, 0);                              \
                aB = __builtin_amdgcn_mfma_f32_16x16x32_f16(avB[kt],            \
                         Bh[t2][kt], aB, 0, 0, 0);                              \
            }                                                                   \
            pA[t2] = aA[0]; pB[t2] = aB[0];                                     \
        }                                                                       \
        {                                                                       \
            float gi = sigm(pA[0]), gf = sigm(pA[1]);                           \
            float gg = tanh_f(pA[2]), go = sigm(pA[3]);                         \
            cstA = gf * cstA + gi * gg;                                         \
            float hn = go * tanh_f(cstA);                                       \
            if (wr16) Hb1[0][(RB_) ^ 1][un] = (_Float16)hn;                     \
            if ((T_) < lenA) { meanA += hn; mxA = fmaxf(mxA, hn); }             \
            if ((T_) == lenA - 1) lastA = hn;                                   \
        }                                                                       \
        {                                                                       \
            float gi = sigm(pB[0]), gf = sigm(pB[1]);                           \
            float gg = tanh_f(pB[2]), go = sigm(pB[3]);                         \
            cstB = gf * cstB + gi * gg;                                         \
            float hn = go * tanh_f(cstB);                                       \
            if (wr16) Hb1[1][(RB_) ^ 1][un] = (_Float16)hn;                     \
            if ((T_) < lenB) { meanB += hn; mxB = fmaxf(mxB, hn); }             \
            if ((T_) == lenB - 1) lastB = hn;                                   \
        }                                                                       \
        bar_lds();                                                              \
    } while (0)

        for (int ch = 0; ch < NCH; ++ch) {
            if (tid == 0) {  // acquire gate
                int guard = 0;
                while (__hip_atomic_load(&flags[p * NCH + ch], __ATOMIC_ACQUIRE,
                                         __HIP_MEMORY_SCOPE_AGENT) != ch + 1) {
                    __builtin_amdgcn_s_sleep(8);
                    if (++guard > (1 << 22)) break;  // hang guard
                }
            }
            __syncthreads();
            // ---- chunk GEMMs (Bi shared): Qs[q][j][un*4+t2] = b1 + W_ih1.h0 ----
            f16x8 Bi[4][4];  // reloaded per chunk (keeps step-loop pressure low)
#pragma unroll
            for (int t2 = 0; t2 < 4; ++t2)
#pragma unroll
                for (int kt = 0; kt < 4; ++kt)
                    Bi[t2][kt] = load_frag(W_ih1 + (t2 * HH + un) * HH, kt, lh);
#pragma unroll
            for (int q = 0; q < 2; ++q) {
                const _Float16* hbase =
                    h0g + ((size_t)(q ? bB : bA) * TT + ch * CH) * HH;
#pragma unroll
                for (int mt = 0; mt < 4; ++mt) {
                    f16x8 am[4];  // A[m=c][k=kt*32+lh*8+j]
#pragma unroll
                    for (int kt = 0; kt < 4; ++kt)
                        am[kt] = *(const f16x8*)(hbase + (mt * 16 + c) * HH + kt * 32 + lh * 8);
                    f32x4 qa[4];
#pragma unroll
                    for (int t2 = 0; t2 < 4; ++t2) {
                        qa[t2] = (f32x4){0.f, 0.f, 0.f, 0.f};
#pragma unroll
                        for (int kt = 0; kt < 4; ++kt)
                            qa[t2] = __builtin_amdgcn_mfma_f32_16x16x32_f16(
                                am[kt], Bi[t2][kt], qa[t2], 0, 0, 0);
                    }
#pragma unroll
                    for (int r = 0; r < 4; ++r) {  // C row m = 4*lh + r
                        f16x4 qv;
#pragma unroll
                        for (int t2 = 0; t2 < 4; ++t2)
                            qv[t2] = (_Float16)(qa[t2][r] + bb1[t2]);
                        *(f16x4*)&Qs[q][mt * 16 + 4 * lh + r][un * 4] = qv;
                    }
                }
            }
            __syncthreads();  // Qs visible to all waves
            // ---- 64 dual recurrence steps, gates from LDS ----
            const int t0 = ch * CH;
            for (int j = 0; j < CH; j += 2) {
                CSTEP(t0 + j, 0);
                CSTEP(t0 + j + 1, 1);
            }
        }
#undef CSTEP
        if (wr16) {
            pooled[bA * 384 + un] = meanA / (float)lenA;
            pooled[bA * 384 + 128 + un] = mxA;
            pooled[bA * 384 + 256 + un] = lastA;
            pooled[bB * 384 + un] = meanB / (float)lenB;
            pooled[bB * 384 + 128 + un] = mxB;
            pooled[bB * 384 + 256 + un] = lastB;
        }
    }
}

// ---------------- head: [B,3H] @ [3H,C]^T + bias ----------------
__global__ __launch_bounds__(448) void k_head(
    const float* __restrict__ pooled, const float* __restrict__ lin_w,
    const float* __restrict__ lin_b, float* __restrict__ out) {
    int tid = threadIdx.x;  // 448 = 64*7
    int b = tid / 7, cc = tid % 7;
    const float* p = pooled + b * 384;
    const float* wr = lin_w + cc * 384;
    float a0 = 0.f, a1 = 0.f, a2 = 0.f, a3 = 0.f;
#pragma unroll
    for (int k = 0; k < 384; k += 4) {
        a0 += p[k + 0] * wr[k + 0];
        a1 += p[k + 1] * wr[k + 1];
        a2 += p[k + 2] * wr[k + 2];
        a3 += p[k + 3] * wr[k + 3];
    }
    out[tid] = lin_b[cc] + ((a0 + a1) + (a2 + a3));
}

extern "C" void kernel_launch(void* const* d_in, const int* in_sizes, int n_in,
                              void* d_out, int out_size, void* d_ws, size_t ws_size,
                              hipStream_t stream) {
    const float* x     = (const float*)d_in[0];
    const int*   lens  = (const int*)d_in[1];
    const float* ff_w  = (const float*)d_in[2];
    const float* ff_b  = (const float*)d_in[3];
    const float* W_ih0 = (const float*)d_in[4];
    const float* W_hh0 = (const float*)d_in[5];
    const float* b0    = (const float*)d_in[6];
    const float* W_ih1 = (const float*)d_in[7];
    const float* W_hh1 = (const float*)d_in[8];
    const float* b1    = (const float*)d_in[9];
    const float* lin_w = (const float*)d_in[10];
    const float* lin_b = (const float*)d_in[11];
    float* out = (float*)d_out;

    char* ws = (char*)d_ws;
    const size_t HBYTES = (size_t)BB * TT * HH * 2;  // 32 MB fp16 h0
    _Float16* h0g = (_Float16*)ws;
    int* flags    = (int*)(ws + HBYTES);             // 32*32 ints (poison-safe)
    float* pooled = (float*)(ws + HBYTES + 8192);

    k_pipe<<<dim3(2 * NPB), dim3(512), 0, stream>>>(
        x, lens, ff_w, ff_b, W_ih0, W_hh0, b0, W_ih1, W_hh1, b1, h0g, flags, pooled);
    k_head<<<dim3(1), dim3(448), 0, stream>>>(pooled, lin_w, lin_b, out);
}